// Round 1
// baseline (2270.203 us; speedup 1.0000x reference)
//
#include <hip/hip_runtime.h>

#define NNODES 10000
#define NEDGES 160000
#define HCDIM  512
#define NHEAD  8
#define CDIM   64
#define SLOPE  0.2f

// ---------------- atomics ----------------
__device__ inline void atomicMaxFloat(float* addr, float val) {
    int* ai = (int*)addr;
    int old = *ai;
    while (true) {
        float fold = __int_as_float(old);
        if (fold >= val) return;           // NaN-init (-NaN) compares false -> replace
        int prev = atomicCAS(ai, old, __float_as_int(val));
        if (prev == old) return;
        old = prev;
    }
}

__device__ inline void atomAddF(float* p, float v) {
#if defined(__HIP_PLATFORM_AMD__)
    unsafeAtomicAdd(p, v);                 // hw global_atomic_add_f32
#else
    atomicAdd(p, v);
#endif
}

// ---------------- GEMM: Y = A(MxK) @ W(KxN) + bias ----------------
#define BM 64
#define BN 64
#define BK 16
__global__ __launch_bounds__(256) void gemm_bias(
    const float* __restrict__ A, const float* __restrict__ W,
    const float* __restrict__ bias, float* __restrict__ Y,
    int M, int K, int Nc) {
    __shared__ float As[BK][BM + 1];
    __shared__ float Bs[BK][BN + 1];
    const int bm = blockIdx.x * BM;
    const int bn = blockIdx.y * BN;
    const int tid = threadIdx.x;
    const int tx = tid % 16;    // col group
    const int ty = tid / 16;    // row group
    float acc[4][4] = {};
    for (int k0 = 0; k0 < K; k0 += BK) {
        #pragma unroll
        for (int i = 0; i < 4; i++) {
            int idx = tid + i * 256;       // 0..1023
            int r = idx / BK, c = idx % BK;
            int gr = bm + r, gc = k0 + c;
            As[c][r] = (gr < M && gc < K) ? A[(size_t)gr * K + gc] : 0.f;
        }
        #pragma unroll
        for (int i = 0; i < 4; i++) {
            int idx = tid + i * 256;
            int r = idx / BN, c = idx % BN;
            int gr = k0 + r, gc = bn + c;
            Bs[r][c] = (gr < K && gc < Nc) ? W[(size_t)gr * Nc + gc] : 0.f;
        }
        __syncthreads();
        #pragma unroll
        for (int kk = 0; kk < BK; kk++) {
            float a[4], b[4];
            #pragma unroll
            for (int i = 0; i < 4; i++) a[i] = As[kk][ty * 4 + i];
            #pragma unroll
            for (int j = 0; j < 4; j++) b[j] = Bs[kk][tx * 4 + j];
            #pragma unroll
            for (int i = 0; i < 4; i++)
                #pragma unroll
                for (int j = 0; j < 4; j++) acc[i][j] += a[i] * b[j];
        }
        __syncthreads();
    }
    #pragma unroll
    for (int i = 0; i < 4; i++) {
        int gr = bm + ty * 4 + i;
        if (gr >= M) continue;
        #pragma unroll
        for (int j = 0; j < 4; j++) {
            int gc = bn + tx * 4 + j;
            if (gc < Nc) Y[(size_t)gr * Nc + gc] = acc[i][j] + bias[gc];
        }
    }
}

// ---------------- edge logits + segment max ----------------
// one wave (64 lanes) per edge; lane = channel within head; loop over 8 heads
__global__ __launch_bounds__(256) void edge_logits(
    const int* __restrict__ ei, const float* __restrict__ eattr,
    const float* __restrict__ xl, const float* __restrict__ xr,
    const float* __restrict__ We, const float* __restrict__ att,
    float* __restrict__ elog, float* __restrict__ smax) {
    const int wave = (blockIdx.x * blockDim.x + threadIdx.x) >> 6;
    const int lane = threadIdx.x & 63;
    if (wave >= NEDGES) return;
    const int src = ei[wave];
    const int dst = ei[NEDGES + wave];
    float ea[8];
    #pragma unroll
    for (int k = 0; k < 8; k++) ea[k] = eattr[(size_t)wave * 8 + k];
    const float* pl = xl + (size_t)src * HCDIM;
    const float* pr = xr + (size_t)dst * HCDIM;
    #pragma unroll
    for (int h = 0; h < NHEAD; h++) {
        const int c = h * CDIM + lane;
        float m = pl[c] + pr[c];
        #pragma unroll
        for (int k = 0; k < 8; k++) m += ea[k] * We[k * HCDIM + c];
        float lr = m > 0.f ? m : SLOPE * m;
        float v = lr * att[c];
        #pragma unroll
        for (int off = 32; off > 0; off >>= 1) v += __shfl_xor(v, off, 64);
        if (lane == 0) {
            elog[(size_t)wave * NHEAD + h] = v;
            atomicMaxFloat(&smax[dst * NHEAD + h], v);
        }
    }
}

// ---------------- exp + segment denom ----------------
__global__ __launch_bounds__(256) void exp_denom(
    const int* __restrict__ ei, float* __restrict__ elog,
    const float* __restrict__ smax, float* __restrict__ denom) {
    const int t = blockIdx.x * blockDim.x + threadIdx.x;
    if (t >= NEDGES * NHEAD) return;
    const int e = t >> 3, h = t & 7;
    const int dst = ei[NEDGES + e];
    float ex = expf(elog[t] - smax[dst * NHEAD + h]);
    elog[t] = ex;   // in-place: elog now holds exp values
    atomAddF(&denom[dst * NHEAD + h], ex);
}

// ---------------- weighted aggregation (scatter-add) ----------------
__global__ __launch_bounds__(256) void aggregate(
    const int* __restrict__ ei, const float* __restrict__ exv,
    const float* __restrict__ denom, const float* __restrict__ xl,
    float* __restrict__ agg) {
    const int wave = (blockIdx.x * blockDim.x + threadIdx.x) >> 6;
    const int lane = threadIdx.x & 63;
    if (wave >= NEDGES) return;
    const int src = ei[wave];
    const int dst = ei[NEDGES + wave];
    const float* pl = xl + (size_t)src * HCDIM;
    float* pd = agg + (size_t)dst * HCDIM;
    #pragma unroll
    for (int h = 0; h < NHEAD; h++) {
        float alpha = exv[(size_t)wave * NHEAD + h] / (denom[dst * NHEAD + h] + 1e-16f);
        atomAddF(&pd[h * CDIM + lane], alpha * pl[h * CDIM + lane]);
    }
}

// ---------------- output bias + model-level leaky relu ----------------
__global__ __launch_bounds__(256) void bias_act(
    const float* __restrict__ agg, const float* __restrict__ bo,
    float* __restrict__ hout) {
    const int t = blockIdx.x * blockDim.x + threadIdx.x;
    if (t >= NNODES * HCDIM) return;
    float v = agg[t] + bo[t & (HCDIM - 1)];
    hout[t] = v > 0.f ? v : SLOPE * v;
}

// ---------------- final linear: y = h @ Wf + bf ----------------
__global__ __launch_bounds__(256) void final_linear(
    const float* __restrict__ h, const float* __restrict__ Wf,
    const float* __restrict__ bf, float* __restrict__ y) {
    const int t = blockIdx.x * blockDim.x + threadIdx.x;
    if (t >= NNODES * 4) return;
    const int n = t >> 2, cls = t & 3;
    const float* ph = h + (size_t)n * HCDIM;
    float acc = bf[cls];
    for (int k = 0; k < HCDIM; k++) acc += ph[k] * Wf[k * 4 + cls];
    y[t] = acc;
}

extern "C" void kernel_launch(void* const* d_in, const int* in_sizes, int n_in,
                              void* d_out, int out_size, void* d_ws, size_t ws_size,
                              hipStream_t stream) {
    const float* x     = (const float*)d_in[0];
    const int*   ei    = (const int*)d_in[1];
    const float* eattr = (const float*)d_in[2];
    const float* Wl[3] = {(const float*)d_in[3],  (const float*)d_in[10], (const float*)d_in[17]};
    const float* bl[3] = {(const float*)d_in[4],  (const float*)d_in[11], (const float*)d_in[18]};
    const float* Wr[3] = {(const float*)d_in[5],  (const float*)d_in[12], (const float*)d_in[19]};
    const float* br[3] = {(const float*)d_in[6],  (const float*)d_in[13], (const float*)d_in[20]};
    const float* We[3] = {(const float*)d_in[7],  (const float*)d_in[14], (const float*)d_in[21]};
    const float* at[3] = {(const float*)d_in[8],  (const float*)d_in[15], (const float*)d_in[22]};
    const float* bo[3] = {(const float*)d_in[9],  (const float*)d_in[16], (const float*)d_in[23]};
    const float* Wf    = (const float*)d_in[24];
    const float* bf    = (const float*)d_in[25];

    float* ws    = (float*)d_ws;
    float* hbuf  = ws;                                  // N*HC
    float* xl    = hbuf + (size_t)NNODES * HCDIM;       // N*HC
    float* xr    = xl   + (size_t)NNODES * HCDIM;       // N*HC (doubles as agg)
    float* elog  = xr   + (size_t)NNODES * HCDIM;       // E*NH
    float* smax  = elog + (size_t)NEDGES * NHEAD;       // N*NH
    float* denom = smax + (size_t)NNODES * NHEAD;       // N*NH

    const float* hin = x;
    int K = 16;
    const dim3 gemm_grid((NNODES + BM - 1) / BM, HCDIM / BN);
    for (int l = 0; l < 3; l++) {
        gemm_bias<<<gemm_grid, 256, 0, stream>>>(hin, Wl[l], bl[l], xl, NNODES, K, HCDIM);
        gemm_bias<<<gemm_grid, 256, 0, stream>>>(hin, Wr[l], br[l], xr, NNODES, K, HCDIM);
        hipMemsetAsync(smax, 0xFF, (size_t)NNODES * NHEAD * 4, stream);   // -NaN sentinel
        hipMemsetAsync(denom, 0,   (size_t)NNODES * NHEAD * 4, stream);
        edge_logits<<<NEDGES / 4, 256, 0, stream>>>(ei, eattr, xl, xr, We[l], at[l], elog, smax);
        exp_denom<<<(NEDGES * NHEAD + 255) / 256, 256, 0, stream>>>(ei, elog, smax, denom);
        hipMemsetAsync(xr, 0, (size_t)NNODES * HCDIM * 4, stream);        // xr becomes agg
        aggregate<<<NEDGES / 4, 256, 0, stream>>>(ei, elog, denom, xl, xr);
        bias_act<<<(NNODES * HCDIM + 255) / 256, 256, 0, stream>>>(xr, bo[l], hbuf);
        hin = hbuf;
        K = HCDIM;
    }
    final_linear<<<(NNODES * 4 + 255) / 256, 256, 0, stream>>>(hbuf, Wf, bf, (float*)d_out);
}

// Round 2
// 1402.643 us; speedup vs baseline: 1.6185x; 1.6185x over previous
//
#include <hip/hip_runtime.h>

#define NNODES 10000
#define NEDGES 160000
#define HCDIM  512
#define NHEAD  8
#define CDIM   64
#define SLOPE  0.2f

// ---------------- GEMM: Y = A(MxK) @ W(KxN) + bias ----------------
#define BM 64
#define BN 64
#define BK 16
__global__ __launch_bounds__(256) void gemm_bias(
    const float* __restrict__ A, const float* __restrict__ W,
    const float* __restrict__ bias, float* __restrict__ Y,
    int M, int K, int Nc) {
    __shared__ float As[BK][BM + 1];
    __shared__ float Bs[BK][BN + 1];
    const int bm = blockIdx.x * BM;
    const int bn = blockIdx.y * BN;
    const int tid = threadIdx.x;
    const int tx = tid % 16;
    const int ty = tid / 16;
    float acc[4][4] = {};
    for (int k0 = 0; k0 < K; k0 += BK) {
        #pragma unroll
        for (int i = 0; i < 4; i++) {
            int idx = tid + i * 256;
            int r = idx / BK, c = idx % BK;
            int gr = bm + r, gc = k0 + c;
            As[c][r] = (gr < M && gc < K) ? A[(size_t)gr * K + gc] : 0.f;
        }
        #pragma unroll
        for (int i = 0; i < 4; i++) {
            int idx = tid + i * 256;
            int r = idx / BN, c = idx % BN;
            int gr = k0 + r, gc = bn + c;
            Bs[r][c] = (gr < K && gc < Nc) ? W[(size_t)gr * Nc + gc] : 0.f;
        }
        __syncthreads();
        #pragma unroll
        for (int kk = 0; kk < BK; kk++) {
            float a[4], b[4];
            #pragma unroll
            for (int i = 0; i < 4; i++) a[i] = As[kk][ty * 4 + i];
            #pragma unroll
            for (int j = 0; j < 4; j++) b[j] = Bs[kk][tx * 4 + j];
            #pragma unroll
            for (int i = 0; i < 4; i++)
                #pragma unroll
                for (int j = 0; j < 4; j++) acc[i][j] += a[i] * b[j];
        }
        __syncthreads();
    }
    #pragma unroll
    for (int i = 0; i < 4; i++) {
        int gr = bm + ty * 4 + i;
        if (gr >= M) continue;
        #pragma unroll
        for (int j = 0; j < 4; j++) {
            int gc = bn + tx * 4 + j;
            if (gc < Nc) Y[(size_t)gr * Nc + gc] = acc[i][j] + bias[gc];
        }
    }
}

// ---------------- CSR build (once per call; graph static) ----------------
__global__ __launch_bounds__(256) void hist_deg(const int* __restrict__ ei, int* __restrict__ deg) {
    const int e = blockIdx.x * blockDim.x + threadIdx.x;
    if (e >= NEDGES) return;
    atomicAdd(&deg[ei[NEDGES + e]], 1);
}

__global__ __launch_bounds__(256) void scan_deg(const int* __restrict__ deg,
                                                int* __restrict__ rowptr,
                                                int* __restrict__ cursor) {
    __shared__ int buf[256];
    __shared__ int sbase;
    if (threadIdx.x == 0) { sbase = 0; rowptr[0] = 0; cursor[0] = 0; }
    __syncthreads();
    for (int start = 0; start < NNODES; start += 256) {
        int i = start + threadIdx.x;
        int v = (i < NNODES) ? deg[i] : 0;
        buf[threadIdx.x] = v;
        __syncthreads();
        #pragma unroll
        for (int off = 1; off < 256; off <<= 1) {
            int t = (threadIdx.x >= off) ? buf[threadIdx.x - off] : 0;
            __syncthreads();
            buf[threadIdx.x] += t;
            __syncthreads();
        }
        int incl = buf[threadIdx.x] + sbase;
        if (i < NNODES) { rowptr[i + 1] = incl; cursor[i + 1] = incl; }
        __syncthreads();
        if (threadIdx.x == 0) sbase += buf[255];
        __syncthreads();
    }
}

__global__ __launch_bounds__(256) void fill_csr(const int* __restrict__ ei,
                                                int* __restrict__ cursor,
                                                int* __restrict__ csr_src,
                                                int* __restrict__ csr_eid) {
    const int e = blockIdx.x * blockDim.x + threadIdx.x;
    if (e >= NEDGES) return;
    const int dst = ei[NEDGES + e];
    const int pos = atomicAdd(&cursor[dst], 1);
    csr_src[pos] = ei[e];
    csr_eid[pos] = e;
}

// ---------------- edge logits (no atomics) ----------------
// one wave (64 lanes) per edge; lane = channel within head; loop over 8 heads
__global__ __launch_bounds__(256) void edge_logits(
    const int* __restrict__ ei, const float* __restrict__ eattr,
    const float* __restrict__ xl, const float* __restrict__ xr,
    const float* __restrict__ We, const float* __restrict__ att,
    float* __restrict__ elog) {
    const int wave = (blockIdx.x * blockDim.x + threadIdx.x) >> 6;
    const int lane = threadIdx.x & 63;
    if (wave >= NEDGES) return;
    const int src = ei[wave];
    const int dst = ei[NEDGES + wave];
    float ea[8];
    #pragma unroll
    for (int k = 0; k < 8; k++) ea[k] = eattr[(size_t)wave * 8 + k];
    const float* pl = xl + (size_t)src * HCDIM;
    const float* pr = xr + (size_t)dst * HCDIM;
    #pragma unroll
    for (int h = 0; h < NHEAD; h++) {
        const int c = h * CDIM + lane;
        float m = pl[c] + pr[c];
        #pragma unroll
        for (int k = 0; k < 8; k++) m += ea[k] * We[k * HCDIM + c];
        float lr = m > 0.f ? m : SLOPE * m;
        float v = lr * att[c];
        #pragma unroll
        for (int off = 32; off > 0; off >>= 1) v += __shfl_xor(v, off, 64);
        if (lane == 0) elog[(size_t)wave * NHEAD + h] = v;
    }
}

// ---------------- fused softmax + aggregation + bias + act, per dst node ----------------
#define AGG_T 128
#define CH 64
__global__ __launch_bounds__(AGG_T) void node_aggregate(
    const int* __restrict__ rowptr, const int* __restrict__ csr_src,
    const int* __restrict__ csr_eid, const float* __restrict__ elog,
    const float* __restrict__ xl, const float* __restrict__ bo,
    float* __restrict__ hout) {
    const int n = blockIdx.x;
    const int tid = threadIdx.x;
    const int beg = rowptr[n];
    const int deg = rowptr[n + 1] - beg;

    __shared__ float sm[NHEAD], sd[NHEAD];
    __shared__ float salpha[CH * NHEAD];
    __shared__ int ssrc[CH];

    if (tid < NHEAD) {
        float m = -1e30f;
        for (int j = 0; j < deg; j++)
            m = fmaxf(m, elog[(size_t)csr_eid[beg + j] * NHEAD + tid]);
        float d = 0.f;
        for (int j = 0; j < deg; j++)
            d += __expf(elog[(size_t)csr_eid[beg + j] * NHEAD + tid] - m);
        sm[tid] = m;
        sd[tid] = d + 1e-16f;
    }

    float4 acc = {0.f, 0.f, 0.f, 0.f};
    const int c0 = tid * 4;          // 4 contiguous channels, all in head c0/64
    const int h = tid >> 4;

    for (int base = 0; base < deg; base += CH) {
        const int cnt = min(CH, deg - base);
        __syncthreads();             // sm/sd ready (first iter) + salpha reuse safe
        for (int t = tid; t < cnt * NHEAD; t += AGG_T) {
            int j = t >> 3, hh = t & 7;
            salpha[t] = __expf(elog[(size_t)csr_eid[beg + base + j] * NHEAD + hh] - sm[hh]) / sd[hh];
        }
        for (int t = tid; t < cnt; t += AGG_T) ssrc[t] = csr_src[beg + base + t];
        __syncthreads();
        for (int j = 0; j < cnt; j++) {
            const float a = salpha[j * NHEAD + h];
            const float4 xv = *(const float4*)(xl + (size_t)ssrc[j] * HCDIM + c0);
            acc.x += a * xv.x; acc.y += a * xv.y; acc.z += a * xv.z; acc.w += a * xv.w;
        }
    }

    const float4 b = *(const float4*)(bo + c0);
    float4 o;
    o.x = acc.x + b.x; o.y = acc.y + b.y; o.z = acc.z + b.z; o.w = acc.w + b.w;
    o.x = o.x > 0.f ? o.x : SLOPE * o.x;
    o.y = o.y > 0.f ? o.y : SLOPE * o.y;
    o.z = o.z > 0.f ? o.z : SLOPE * o.z;
    o.w = o.w > 0.f ? o.w : SLOPE * o.w;
    *(float4*)(hout + (size_t)n * HCDIM + c0) = o;
}

// ---------------- final linear: y = h @ Wf + bf ----------------
__global__ __launch_bounds__(256) void final_linear(
    const float* __restrict__ h, const float* __restrict__ Wf,
    const float* __restrict__ bf, float* __restrict__ y) {
    const int t = blockIdx.x * blockDim.x + threadIdx.x;
    if (t >= NNODES * 4) return;
    const int n = t >> 2, cls = t & 3;
    const float* ph = h + (size_t)n * HCDIM;
    float acc = bf[cls];
    for (int k = 0; k < HCDIM; k++) acc += ph[k] * Wf[k * 4 + cls];
    y[t] = acc;
}

extern "C" void kernel_launch(void* const* d_in, const int* in_sizes, int n_in,
                              void* d_out, int out_size, void* d_ws, size_t ws_size,
                              hipStream_t stream) {
    const float* x     = (const float*)d_in[0];
    const int*   ei    = (const int*)d_in[1];
    const float* eattr = (const float*)d_in[2];
    const float* Wl[3] = {(const float*)d_in[3],  (const float*)d_in[10], (const float*)d_in[17]};
    const float* bl[3] = {(const float*)d_in[4],  (const float*)d_in[11], (const float*)d_in[18]};
    const float* Wr[3] = {(const float*)d_in[5],  (const float*)d_in[12], (const float*)d_in[19]};
    const float* br[3] = {(const float*)d_in[6],  (const float*)d_in[13], (const float*)d_in[20]};
    const float* We[3] = {(const float*)d_in[7],  (const float*)d_in[14], (const float*)d_in[21]};
    const float* at[3] = {(const float*)d_in[8],  (const float*)d_in[15], (const float*)d_in[22]};
    const float* bo[3] = {(const float*)d_in[9],  (const float*)d_in[16], (const float*)d_in[23]};
    const float* Wf    = (const float*)d_in[24];
    const float* bf    = (const float*)d_in[25];

    float* ws    = (float*)d_ws;
    float* hbuf  = ws;                                   // N*HC
    float* xl    = hbuf + (size_t)NNODES * HCDIM;        // N*HC
    float* xr    = xl   + (size_t)NNODES * HCDIM;        // N*HC
    float* elog  = xr   + (size_t)NNODES * HCDIM;        // E*NH
    int*   deg     = (int*)(elog + (size_t)NEDGES * NHEAD);  // N
    int*   rowptr  = deg + NNODES;                       // N+1
    int*   cursor  = rowptr + NNODES + 1;                // N+1
    int*   csr_src = cursor + NNODES + 1;                // E
    int*   csr_eid = csr_src + NEDGES;                   // E

    // ---- CSR build (graph static across layers) ----
    hipMemsetAsync(deg, 0, (size_t)NNODES * 4, stream);
    hist_deg<<<(NEDGES + 255) / 256, 256, 0, stream>>>(ei, deg);
    scan_deg<<<1, 256, 0, stream>>>(deg, rowptr, cursor);
    fill_csr<<<(NEDGES + 255) / 256, 256, 0, stream>>>(ei, cursor, csr_src, csr_eid);

    const float* hin = x;
    int K = 16;
    const dim3 gemm_grid((NNODES + BM - 1) / BM, HCDIM / BN);
    for (int l = 0; l < 3; l++) {
        gemm_bias<<<gemm_grid, 256, 0, stream>>>(hin, Wl[l], bl[l], xl, NNODES, K, HCDIM);
        gemm_bias<<<gemm_grid, 256, 0, stream>>>(hin, Wr[l], br[l], xr, NNODES, K, HCDIM);
        edge_logits<<<NEDGES / 4, 256, 0, stream>>>(ei, eattr, xl, xr, We[l], at[l], elog);
        node_aggregate<<<NNODES, AGG_T, 0, stream>>>(rowptr, csr_src, csr_eid, elog, xl, bo[l], hbuf);
        hin = hbuf;
        K = HCDIM;
    }
    final_linear<<<(NNODES * 4 + 255) / 256, 256, 0, stream>>>(hbuf, Wf, bf, (float*)d_out);
}

// Round 3
// 947.591 us; speedup vs baseline: 2.3958x; 1.4802x over previous
//
#include <hip/hip_runtime.h>

#define NNODES 10000
#define NEDGES 160000
#define HCDIM  512
#define NHEAD  8
#define CDIM   64
#define SLOPE  0.2f

// ---------------- GEMM: Y = A(MxK) @ W(KxN) + bias ----------------
#define BM 64
#define BN 64
#define BK 16
__global__ __launch_bounds__(256) void gemm_bias(
    const float* __restrict__ A, const float* __restrict__ W,
    const float* __restrict__ bias, float* __restrict__ Y,
    int M, int K, int Nc) {
    __shared__ float As[BK][BM + 1];
    __shared__ float Bs[BK][BN + 1];
    const int bm = blockIdx.x * BM;
    const int bn = blockIdx.y * BN;
    const int tid = threadIdx.x;
    const int tx = tid % 16;
    const int ty = tid / 16;
    float acc[4][4] = {};
    for (int k0 = 0; k0 < K; k0 += BK) {
        #pragma unroll
        for (int i = 0; i < 4; i++) {
            int idx = tid + i * 256;
            int r = idx / BK, c = idx % BK;
            int gr = bm + r, gc = k0 + c;
            As[c][r] = (gr < M && gc < K) ? A[(size_t)gr * K + gc] : 0.f;
        }
        #pragma unroll
        for (int i = 0; i < 4; i++) {
            int idx = tid + i * 256;
            int r = idx / BN, c = idx % BN;
            int gr = k0 + r, gc = bn + c;
            Bs[r][c] = (gr < K && gc < Nc) ? W[(size_t)gr * Nc + gc] : 0.f;
        }
        __syncthreads();
        #pragma unroll
        for (int kk = 0; kk < BK; kk++) {
            float a[4], b[4];
            #pragma unroll
            for (int i = 0; i < 4; i++) a[i] = As[kk][ty * 4 + i];
            #pragma unroll
            for (int j = 0; j < 4; j++) b[j] = Bs[kk][tx * 4 + j];
            #pragma unroll
            for (int i = 0; i < 4; i++)
                #pragma unroll
                for (int j = 0; j < 4; j++) acc[i][j] += a[i] * b[j];
        }
        __syncthreads();
    }
    #pragma unroll
    for (int i = 0; i < 4; i++) {
        int gr = bm + ty * 4 + i;
        if (gr >= M) continue;
        #pragma unroll
        for (int j = 0; j < 4; j++) {
            int gc = bn + tx * 4 + j;
            if (gc < Nc) Y[(size_t)gr * Nc + gc] = acc[i][j] + bias[gc];
        }
    }
}

// ---------------- CSR build (once per call; graph static) ----------------
__global__ __launch_bounds__(256) void hist_deg(const int* __restrict__ ei, int* __restrict__ deg) {
    const int e = blockIdx.x * blockDim.x + threadIdx.x;
    if (e >= NEDGES) return;
    atomicAdd(&deg[ei[NEDGES + e]], 1);
}

__global__ __launch_bounds__(256) void scan_deg(const int* __restrict__ deg,
                                                int* __restrict__ rowptr,
                                                int* __restrict__ cursor) {
    __shared__ int buf[256];
    __shared__ int sbase;
    if (threadIdx.x == 0) { sbase = 0; rowptr[0] = 0; cursor[0] = 0; }
    __syncthreads();
    for (int start = 0; start < NNODES; start += 256) {
        int i = start + threadIdx.x;
        int v = (i < NNODES) ? deg[i] : 0;
        buf[threadIdx.x] = v;
        __syncthreads();
        #pragma unroll
        for (int off = 1; off < 256; off <<= 1) {
            int t = (threadIdx.x >= off) ? buf[threadIdx.x - off] : 0;
            __syncthreads();
            buf[threadIdx.x] += t;
            __syncthreads();
        }
        int incl = buf[threadIdx.x] + sbase;
        if (i < NNODES) { rowptr[i + 1] = incl; cursor[i + 1] = incl; }
        __syncthreads();
        if (threadIdx.x == 0) sbase += buf[255];
        __syncthreads();
    }
}

// also gathers edge_attr into CSR order (reused by all 3 layers)
__global__ __launch_bounds__(256) void fill_csr(const int* __restrict__ ei,
                                                const float* __restrict__ eattr,
                                                int* __restrict__ cursor,
                                                int* __restrict__ csr_src,
                                                float* __restrict__ ea_csr) {
    const int e = blockIdx.x * blockDim.x + threadIdx.x;
    if (e >= NEDGES) return;
    const int dst = ei[NEDGES + e];
    const int pos = atomicAdd(&cursor[dst], 1);
    csr_src[pos] = ei[e];
    const float4 v0 = *(const float4*)(eattr + (size_t)e * 8);
    const float4 v1 = *(const float4*)(eattr + (size_t)e * 8 + 4);
    *(float4*)(ea_csr + (size_t)pos * 8) = v0;
    *(float4*)(ea_csr + (size_t)pos * 8 + 4) = v1;
}

// ---- fused logits + online softmax + aggregation + bias + act, per dst node ----
// 128 threads/block: thread owns 4 channels c0=tid*4, head h=tid>>4 (16 lanes/head).
#define AT  128
#define ECH 32
__global__ __launch_bounds__(AT) void node_attn_agg(
    const int* __restrict__ rowptr, const int* __restrict__ csr_src,
    const float* __restrict__ ea_csr, const float* __restrict__ xl,
    const float* __restrict__ xr, const float* __restrict__ We,
    const float* __restrict__ att, const float* __restrict__ bo,
    float* __restrict__ hout) {
    const int n = blockIdx.x;
    const int tid = threadIdx.x;
    const int c0 = tid * 4;
    const int beg = rowptr[n];
    const int deg = rowptr[n + 1] - beg;

    float4 wreg[8];
    #pragma unroll
    for (int k = 0; k < 8; k++) wreg[k] = *(const float4*)(We + k * HCDIM + c0);
    const float4 a4  = *(const float4*)(att + c0);
    const float4 xr4 = *(const float4*)(xr + (size_t)n * HCDIM + c0);

    __shared__ int   ssrc[ECH];
    __shared__ float sea[ECH][8];

    float4 acc = {0.f, 0.f, 0.f, 0.f};
    float m_run = -1e30f, l_run = 0.f;

    for (int base = 0; base < deg; base += ECH) {
        const int cnt = min(ECH, deg - base);
        __syncthreads();
        if (tid < 64) {
            const int j = tid >> 1;
            if (j < cnt)
                *(float4*)&sea[j][(tid & 1) * 4] =
                    *(const float4*)(ea_csr + (size_t)(beg + base + j) * 8 + (tid & 1) * 4);
        } else if (tid < 64 + ECH) {
            const int j = tid - 64;
            if (j < cnt) ssrc[j] = csr_src[beg + base + j];
        }
        __syncthreads();
        for (int j = 0; j < cnt; j++) {
            const float4 xv = *(const float4*)(xl + (size_t)ssrc[j] * HCDIM + c0);
            float4 mm;
            mm.x = xv.x + xr4.x; mm.y = xv.y + xr4.y;
            mm.z = xv.z + xr4.z; mm.w = xv.w + xr4.w;
            #pragma unroll
            for (int k = 0; k < 8; k++) {
                const float ek = sea[j][k];
                mm.x += ek * wreg[k].x; mm.y += ek * wreg[k].y;
                mm.z += ek * wreg[k].z; mm.w += ek * wreg[k].w;
            }
            float4 lr;
            lr.x = mm.x > 0.f ? mm.x : SLOPE * mm.x;
            lr.y = mm.y > 0.f ? mm.y : SLOPE * mm.y;
            lr.z = mm.z > 0.f ? mm.z : SLOPE * mm.z;
            lr.w = mm.w > 0.f ? mm.w : SLOPE * mm.w;
            float pv = lr.x * a4.x + lr.y * a4.y + lr.z * a4.z + lr.w * a4.w;
            pv += __shfl_xor(pv, 1, 64);
            pv += __shfl_xor(pv, 2, 64);
            pv += __shfl_xor(pv, 4, 64);
            pv += __shfl_xor(pv, 8, 64);   // all 16 lanes of this head now hold the logit
            const float m_new = fmaxf(m_run, pv);
            const float fac = __expf(m_run - m_new);   // 0 on first edge (m_run=-1e30)
            const float p   = __expf(pv - m_new);
            acc.x = acc.x * fac + p * xv.x;
            acc.y = acc.y * fac + p * xv.y;
            acc.z = acc.z * fac + p * xv.z;
            acc.w = acc.w * fac + p * xv.w;
            l_run = l_run * fac + p;
            m_run = m_new;
        }
    }

    const float inv = 1.f / (l_run + 1e-16f);
    const float4 b4 = *(const float4*)(bo + c0);
    float4 o;
    o.x = acc.x * inv + b4.x; o.y = acc.y * inv + b4.y;
    o.z = acc.z * inv + b4.z; o.w = acc.w * inv + b4.w;
    o.x = o.x > 0.f ? o.x : SLOPE * o.x;
    o.y = o.y > 0.f ? o.y : SLOPE * o.y;
    o.z = o.z > 0.f ? o.z : SLOPE * o.z;
    o.w = o.w > 0.f ? o.w : SLOPE * o.w;
    *(float4*)(hout + (size_t)n * HCDIM + c0) = o;
}

// ---------------- final linear: y = h @ Wf + bf ----------------
__global__ __launch_bounds__(256) void final_linear(
    const float* __restrict__ h, const float* __restrict__ Wf,
    const float* __restrict__ bf, float* __restrict__ y) {
    const int t = blockIdx.x * blockDim.x + threadIdx.x;
    if (t >= NNODES * 4) return;
    const int n = t >> 2, cls = t & 3;
    const float* ph = h + (size_t)n * HCDIM;
    float acc = bf[cls];
    for (int k = 0; k < HCDIM; k++) acc += ph[k] * Wf[k * 4 + cls];
    y[t] = acc;
}

extern "C" void kernel_launch(void* const* d_in, const int* in_sizes, int n_in,
                              void* d_out, int out_size, void* d_ws, size_t ws_size,
                              hipStream_t stream) {
    const float* x     = (const float*)d_in[0];
    const int*   ei    = (const int*)d_in[1];
    const float* eattr = (const float*)d_in[2];
    const float* Wl[3] = {(const float*)d_in[3],  (const float*)d_in[10], (const float*)d_in[17]};
    const float* bl[3] = {(const float*)d_in[4],  (const float*)d_in[11], (const float*)d_in[18]};
    const float* Wr[3] = {(const float*)d_in[5],  (const float*)d_in[12], (const float*)d_in[19]};
    const float* br[3] = {(const float*)d_in[6],  (const float*)d_in[13], (const float*)d_in[20]};
    const float* We[3] = {(const float*)d_in[7],  (const float*)d_in[14], (const float*)d_in[21]};
    const float* at[3] = {(const float*)d_in[8],  (const float*)d_in[15], (const float*)d_in[22]};
    const float* bo[3] = {(const float*)d_in[9],  (const float*)d_in[16], (const float*)d_in[23]};
    const float* Wf    = (const float*)d_in[24];
    const float* bf    = (const float*)d_in[25];

    float* ws     = (float*)d_ws;
    float* hbuf   = ws;                                    // N*HC
    float* xl     = hbuf + (size_t)NNODES * HCDIM;         // N*HC
    float* xr     = xl   + (size_t)NNODES * HCDIM;         // N*HC
    float* ea_csr = xr   + (size_t)NNODES * HCDIM;         // E*8
    int*   deg     = (int*)(ea_csr + (size_t)NEDGES * 8);  // N
    int*   rowptr  = deg + NNODES;                         // N+1
    int*   cursor  = rowptr + NNODES + 1;                  // N+1
    int*   csr_src = cursor + NNODES + 1;                  // E

    // ---- CSR build (graph static across layers) ----
    hipMemsetAsync(deg, 0, (size_t)NNODES * 4, stream);
    hist_deg<<<(NEDGES + 255) / 256, 256, 0, stream>>>(ei, deg);
    scan_deg<<<1, 256, 0, stream>>>(deg, rowptr, cursor);
    fill_csr<<<(NEDGES + 255) / 256, 256, 0, stream>>>(ei, eattr, cursor, csr_src, ea_csr);

    const float* hin = x;
    int K = 16;
    const dim3 gemm_grid((NNODES + BM - 1) / BM, HCDIM / BN);
    for (int l = 0; l < 3; l++) {
        gemm_bias<<<gemm_grid, 256, 0, stream>>>(hin, Wl[l], bl[l], xl, NNODES, K, HCDIM);
        gemm_bias<<<gemm_grid, 256, 0, stream>>>(hin, Wr[l], br[l], xr, NNODES, K, HCDIM);
        node_attn_agg<<<NNODES, AT, 0, stream>>>(rowptr, csr_src, ea_csr, xl, xr,
                                                 We[l], at[l], bo[l], hbuf);
        hin = hbuf;
        K = HCDIM;
    }
    final_linear<<<(NNODES * 4 + 255) / 256, 256, 0, stream>>>(hbuf, Wf, bf, (float*)d_out);
}

// Round 4
// 460.338 us; speedup vs baseline: 4.9316x; 2.0585x over previous
//
#include <hip/hip_runtime.h>

#define NNODES 10000
#define NEDGES 160000
#define HCDIM  512
#define NHEAD  8
#define CDIM   64
#define SLOPE  0.2f

using short8  = __attribute__((ext_vector_type(8))) short;
using floatx4 = __attribute__((ext_vector_type(4))) float;

__device__ inline unsigned short f2bf(float f) {
    unsigned u = __float_as_uint(f);
    unsigned r = (u + 0x7FFF + ((u >> 16) & 1)) >> 16;   // RNE
    return (unsigned short)r;
}

__device__ inline void gload16(const void* g, void* l) {
    __builtin_amdgcn_global_load_lds(
        (const __attribute__((address_space(1))) unsigned int*)g,
        (__attribute__((address_space(3))) unsigned int*)l, 16, 0, 0);
}

// ---------------- CSR build (once per call; graph static) ----------------
__global__ __launch_bounds__(256) void hist_deg(const int* __restrict__ ei, int* __restrict__ deg) {
    const int e = blockIdx.x * blockDim.x + threadIdx.x;
    if (e >= NEDGES) return;
    atomicAdd(&deg[ei[NEDGES + e]], 1);
}

__global__ __launch_bounds__(256) void scan_deg(const int* __restrict__ deg,
                                                int* __restrict__ rowptr,
                                                int* __restrict__ cursor) {
    __shared__ int buf[256];
    __shared__ int sbase;
    if (threadIdx.x == 0) { sbase = 0; rowptr[0] = 0; cursor[0] = 0; }
    __syncthreads();
    for (int start = 0; start < NNODES; start += 256) {
        int i = start + threadIdx.x;
        int v = (i < NNODES) ? deg[i] : 0;
        buf[threadIdx.x] = v;
        __syncthreads();
        #pragma unroll
        for (int off = 1; off < 256; off <<= 1) {
            int t = (threadIdx.x >= off) ? buf[threadIdx.x - off] : 0;
            __syncthreads();
            buf[threadIdx.x] += t;
            __syncthreads();
        }
        int incl = buf[threadIdx.x] + sbase;
        if (i < NNODES) { rowptr[i + 1] = incl; cursor[i + 1] = incl; }
        __syncthreads();
        if (threadIdx.x == 0) sbase += buf[255];
        __syncthreads();
    }
}

__global__ __launch_bounds__(256) void fill_csr(const int* __restrict__ ei,
                                                const float* __restrict__ eattr,
                                                int* __restrict__ cursor,
                                                int* __restrict__ csr_src,
                                                float* __restrict__ ea_csr) {
    const int e = blockIdx.x * blockDim.x + threadIdx.x;
    if (e >= NEDGES) return;
    const int dst = ei[NEDGES + e];
    const int pos = atomicAdd(&cursor[dst], 1);
    csr_src[pos] = ei[e];
    const float4 v0 = *(const float4*)(eattr + (size_t)e * 8);
    const float4 v1 = *(const float4*)(eattr + (size_t)e * 8 + 4);
    *(float4*)(ea_csr + (size_t)pos * 8) = v0;
    *(float4*)(ea_csr + (size_t)pos * 8 + 4) = v1;
}

// ---------------- weight prep: Wt[n][kp] = bf16(cat(Wl,Wr)^T), zero-padded K ----------------
__global__ __launch_bounds__(256) void wprep(const float* __restrict__ Wl,
                                             const float* __restrict__ Wr,
                                             int K, int Kpad,
                                             unsigned short* __restrict__ Wt) {
    const int t = blockIdx.x * blockDim.x + threadIdx.x;
    if (t >= 1024 * Kpad) return;
    const int n = t / Kpad, kp = t - n * Kpad;
    float v = 0.f;
    if (kp < K) v = (n < 512) ? Wl[kp * 512 + n] : Wr[kp * 512 + (n - 512)];
    Wt[t] = f2bf(v);
}

// ---------------- x -> bf16, K padded 16 -> 32 ----------------
__global__ __launch_bounds__(256) void convert_x(const float* __restrict__ x,
                                                 unsigned short* __restrict__ xb) {
    const int t = blockIdx.x * blockDim.x + threadIdx.x;
    if (t >= NNODES * 32) return;
    const int i = t >> 5, k = t & 31;
    xb[t] = (k < 16) ? f2bf(x[i * 16 + k]) : (unsigned short)0;
}

// ---------------- bf16 MFMA GEMM: [xl|xr] = A(Mx Kp) @ Wt^T + [bl|br] ----------------
// 128x128 tile, 256 thr = 4 waves in 2x2; A row-major [M][Kp] bf16, Wt [1024][Kp] bf16 (B^T)
__global__ __launch_bounds__(256) void mfma_gemm(
    const unsigned short* __restrict__ A, const unsigned short* __restrict__ Wt,
    const float* __restrict__ bl, const float* __restrict__ br,
    float* __restrict__ xl, float* __restrict__ xr, int Kp) {
    __shared__ unsigned short sA[128 * 32];
    __shared__ unsigned short sB[128 * 32];
    const int bm = blockIdx.x * 128;
    const int by = blockIdx.y;
    const int bn = by * 128;
    const int tid = threadIdx.x;
    const int wave = tid >> 6, lane = tid & 63;
    const int wm = wave >> 1, wn = wave & 1;
    const int lm = lane & 15, lq = lane >> 4;

    floatx4 acc[4][4] = {};

    for (int k0 = 0; k0 < Kp; k0 += 32) {
        __syncthreads();
        #pragma unroll
        for (int i = 0; i < 2; i++) {
            const int chunk = i * 256 + wave * 64 + lane;   // 0..511
            const int r = chunk >> 2, kc = chunk & 3;
            int row = bm + r; row = row < NNODES ? row : NNODES - 1;
            gload16(A  + (size_t)row * Kp + k0 + kc * 8, &sA[(i * 256 + wave * 64) * 8]);
            gload16(Wt + (size_t)(bn + r) * Kp + k0 + kc * 8, &sB[(i * 256 + wave * 64) * 8]);
        }
        __syncthreads();
        short8 af[4], bfr[4];
        #pragma unroll
        for (int t = 0; t < 4; t++) {
            af[t]  = *(const short8*)&sA[(wm * 64 + t * 16 + lm) * 32 + lq * 8];
            bfr[t] = *(const short8*)&sB[(wn * 64 + t * 16 + lm) * 32 + lq * 8];
        }
        #pragma unroll
        for (int mt = 0; mt < 4; mt++)
            #pragma unroll
            for (int nt = 0; nt < 4; nt++)
                acc[mt][nt] = __builtin_amdgcn_mfma_f32_16x16x32_bf16(af[mt], bfr[nt], acc[mt][nt], 0, 0, 0);
    }

    float* out        = (by < 4) ? xl : xr;
    const float* bias = (by < 4) ? bl : br;
    const int cb      = (by < 4) ? bn : bn - 512;
    #pragma unroll
    for (int mt = 0; mt < 4; mt++) {
        const int row0 = bm + wm * 64 + mt * 16 + lq * 4;
        #pragma unroll
        for (int nt = 0; nt < 4; nt++) {
            const int col = cb + wn * 64 + nt * 16 + lm;
            const float bv = bias[col];
            #pragma unroll
            for (int r = 0; r < 4; r++) {
                const int row = row0 + r;
                if (row < NNODES) out[(size_t)row * 512 + col] = acc[mt][nt][r] + bv;
            }
        }
    }
}

// ---- fused logits + online softmax + aggregation + bias + act, per dst node ----
#define AT  128
#define ECH 32
__global__ __launch_bounds__(AT) void node_attn_agg(
    const int* __restrict__ rowptr, const int* __restrict__ csr_src,
    const float* __restrict__ ea_csr, const float* __restrict__ xl,
    const float* __restrict__ xr, const float* __restrict__ We,
    const float* __restrict__ att, const float* __restrict__ bo,
    float* __restrict__ hout, unsigned short* __restrict__ hout16) {
    const int n = blockIdx.x;
    const int tid = threadIdx.x;
    const int c0 = tid * 4;
    const int beg = rowptr[n];
    const int deg = rowptr[n + 1] - beg;

    float4 wreg[8];
    #pragma unroll
    for (int k = 0; k < 8; k++) wreg[k] = *(const float4*)(We + k * HCDIM + c0);
    const float4 a4  = *(const float4*)(att + c0);
    const float4 xr4 = *(const float4*)(xr + (size_t)n * HCDIM + c0);

    __shared__ int   ssrc[ECH];
    __shared__ float sea[ECH][8];

    float4 acc = {0.f, 0.f, 0.f, 0.f};
    float m_run = -1e30f, l_run = 0.f;

    for (int base = 0; base < deg; base += ECH) {
        const int cnt = min(ECH, deg - base);
        __syncthreads();
        if (tid < 64) {
            const int j = tid >> 1;
            if (j < cnt)
                *(float4*)&sea[j][(tid & 1) * 4] =
                    *(const float4*)(ea_csr + (size_t)(beg + base + j) * 8 + (tid & 1) * 4);
        } else if (tid < 64 + ECH) {
            const int j = tid - 64;
            if (j < cnt) ssrc[j] = csr_src[beg + base + j];
        }
        __syncthreads();
        for (int j = 0; j < cnt; j++) {
            const float4 xv = *(const float4*)(xl + (size_t)ssrc[j] * HCDIM + c0);
            float4 mm;
            mm.x = xv.x + xr4.x; mm.y = xv.y + xr4.y;
            mm.z = xv.z + xr4.z; mm.w = xv.w + xr4.w;
            #pragma unroll
            for (int k = 0; k < 8; k++) {
                const float ek = sea[j][k];
                mm.x += ek * wreg[k].x; mm.y += ek * wreg[k].y;
                mm.z += ek * wreg[k].z; mm.w += ek * wreg[k].w;
            }
            float4 lr;
            lr.x = mm.x > 0.f ? mm.x : SLOPE * mm.x;
            lr.y = mm.y > 0.f ? mm.y : SLOPE * mm.y;
            lr.z = mm.z > 0.f ? mm.z : SLOPE * mm.z;
            lr.w = mm.w > 0.f ? mm.w : SLOPE * mm.w;
            float pv = lr.x * a4.x + lr.y * a4.y + lr.z * a4.z + lr.w * a4.w;
            pv += __shfl_xor(pv, 1, 64);
            pv += __shfl_xor(pv, 2, 64);
            pv += __shfl_xor(pv, 4, 64);
            pv += __shfl_xor(pv, 8, 64);
            const float m_new = fmaxf(m_run, pv);
            const float fac = __expf(m_run - m_new);
            const float p   = __expf(pv - m_new);
            acc.x = acc.x * fac + p * xv.x;
            acc.y = acc.y * fac + p * xv.y;
            acc.z = acc.z * fac + p * xv.z;
            acc.w = acc.w * fac + p * xv.w;
            l_run = l_run * fac + p;
            m_run = m_new;
        }
    }

    const float inv = 1.f / (l_run + 1e-16f);
    const float4 b4 = *(const float4*)(bo + c0);
    float4 o;
    o.x = acc.x * inv + b4.x; o.y = acc.y * inv + b4.y;
    o.z = acc.z * inv + b4.z; o.w = acc.w * inv + b4.w;
    o.x = o.x > 0.f ? o.x : SLOPE * o.x;
    o.y = o.y > 0.f ? o.y : SLOPE * o.y;
    o.z = o.z > 0.f ? o.z : SLOPE * o.z;
    o.w = o.w > 0.f ? o.w : SLOPE * o.w;
    *(float4*)(hout + (size_t)n * HCDIM + c0) = o;
    ushort4 q;
    q.x = f2bf(o.x); q.y = f2bf(o.y); q.z = f2bf(o.z); q.w = f2bf(o.w);
    *(ushort4*)(hout16 + (size_t)n * HCDIM + c0) = q;
}

// ---------------- final linear: y = h @ Wf + bf ----------------
__global__ __launch_bounds__(256) void final_linear(
    const float* __restrict__ h, const float* __restrict__ Wf,
    const float* __restrict__ bf, float* __restrict__ y) {
    const int t = blockIdx.x * blockDim.x + threadIdx.x;
    if (t >= NNODES * 4) return;
    const int n = t >> 2, cls = t & 3;
    const float* ph = h + (size_t)n * HCDIM;
    float acc = bf[cls];
    for (int k = 0; k < HCDIM; k++) acc += ph[k] * Wf[k * 4 + cls];
    y[t] = acc;
}

extern "C" void kernel_launch(void* const* d_in, const int* in_sizes, int n_in,
                              void* d_out, int out_size, void* d_ws, size_t ws_size,
                              hipStream_t stream) {
    const float* x     = (const float*)d_in[0];
    const int*   ei    = (const int*)d_in[1];
    const float* eattr = (const float*)d_in[2];
    const float* Wl[3] = {(const float*)d_in[3],  (const float*)d_in[10], (const float*)d_in[17]};
    const float* bl[3] = {(const float*)d_in[4],  (const float*)d_in[11], (const float*)d_in[18]};
    const float* Wr[3] = {(const float*)d_in[5],  (const float*)d_in[12], (const float*)d_in[19]};
    const float* br[3] = {(const float*)d_in[6],  (const float*)d_in[13], (const float*)d_in[20]};
    const float* We[3] = {(const float*)d_in[7],  (const float*)d_in[14], (const float*)d_in[21]};
    const float* at[3] = {(const float*)d_in[8],  (const float*)d_in[15], (const float*)d_in[22]};
    const float* bo[3] = {(const float*)d_in[9],  (const float*)d_in[16], (const float*)d_in[23]};
    const float* Wf    = (const float*)d_in[24];
    const float* bf    = (const float*)d_in[25];

    float* ws     = (float*)d_ws;
    float* hbuf   = ws;                                    // N*HC f32
    float* xl     = hbuf + (size_t)NNODES * HCDIM;         // N*HC f32
    float* xr     = xl   + (size_t)NNODES * HCDIM;         // N*HC f32
    float* ea_csr = xr   + (size_t)NNODES * HCDIM;         // E*8 f32
    unsigned short* hb16 = (unsigned short*)(ea_csr + (size_t)NEDGES * 8);  // N*HC bf16
    unsigned short* xb16 = hb16 + (size_t)NNODES * HCDIM;  // N*32 bf16
    unsigned short* Wt   = xb16 + (size_t)NNODES * 32;     // 1024*512 bf16 (reused per layer)
    int* deg     = (int*)(Wt + (size_t)1024 * 512);        // N
    int* rowptr  = deg + NNODES;                           // N+1
    int* cursor  = rowptr + NNODES + 1;                    // N+1
    int* csr_src = cursor + NNODES + 1;                    // E

    // ---- CSR build (graph static across layers) ----
    hipMemsetAsync(deg, 0, (size_t)NNODES * 4, stream);
    hist_deg<<<(NEDGES + 255) / 256, 256, 0, stream>>>(ei, deg);
    scan_deg<<<1, 256, 0, stream>>>(deg, rowptr, cursor);
    fill_csr<<<(NEDGES + 255) / 256, 256, 0, stream>>>(ei, eattr, cursor, csr_src, ea_csr);
    convert_x<<<(NNODES * 32 + 255) / 256, 256, 0, stream>>>(x, xb16);

    const dim3 gg((NNODES + 127) / 128, 8);
    for (int l = 0; l < 3; l++) {
        const int K  = (l == 0) ? 16 : HCDIM;
        const int Kp = (l == 0) ? 32 : HCDIM;
        const unsigned short* Agemm = (l == 0) ? xb16 : hb16;
        wprep<<<(1024 * Kp + 255) / 256, 256, 0, stream>>>(Wl[l], Wr[l], K, Kp, Wt);
        mfma_gemm<<<gg, 256, 0, stream>>>(Agemm, Wt, bl[l], br[l], xl, xr, Kp);
        node_attn_agg<<<NNODES, AT, 0, stream>>>(rowptr, csr_src, ea_csr, xl, xr,
                                                 We[l], at[l], bo[l], hbuf, hb16);
    }
    final_linear<<<(NNODES * 4 + 255) / 256, 256, 0, stream>>>(hbuf, Wf, bf, (float*)d_out);
}